// Round 14
// baseline (143.767 us; speedup 1.0000x reference)
//
#include <hip/hip_runtime.h>

// VQ-VAE forward + EMA update, MI355X.
// Sizes fixed by the reference: B=64, C=D=8, H=W=64, K=512.
constexpr int Kc   = 512;
constexpr int Dc   = 8;
constexpr int HWc  = 4096;            // 64*64
constexpr int CHWc = Dc * HWc;        // 32768
constexpr int Mc   = 64 * HWc;        // 262144 vectors
constexpr int TOTALc = Mc * Dc;       // 2097152 elements of z / z_q

// 8 replica accumulators (one per XCD via blockIdx&7) to cut atomic contention.
constexpr int REP      = 8;
constexpr int RSTRIDE  = 4616;        // 512 counts + 4096 sums + 1 loss + 7 pad
constexpr int ACC_FLOATS = REP * RSTRIDE;   // 36928 floats (~148 KB)
// d_ws float layout:
//   [0 .. ACC_FLOATS)            replica accumulators (counts | sums | loss | pad) x8
//   [ACC_FLOATS .. +512)         e_sq[k]

typedef float v2f  __attribute__((ext_vector_type(2)));
typedef unsigned long long ull;
typedef ull  u64x4 __attribute__((ext_vector_type(4)));

__global__ __launch_bounds__(256) void vq_prep(const float* __restrict__ cb,
                                               float* __restrict__ ws) {
    const int tid = blockIdx.x * 256 + threadIdx.x;
    float4* w4 = (float4*)ws;
    for (int i = tid; i < ACC_FLOATS / 4; i += gridDim.x * 256)
        w4[i] = float4{0.f, 0.f, 0.f, 0.f};
    if (blockIdx.x == 0) {
        for (int k = threadIdx.x; k < Kc; k += 256) {
            float s = 0.f;
#pragma unroll
            for (int c = 0; c < Dc; ++c) {
                const float e = cb[k * Dc + c];
                s = fmaf(e, e, s);
            }
            ws[ACC_FLOATS + k] = s;
        }
    }
}

// 256 blocks x 512 threads; block owns 1024 consecutive vectors.
// VECTOR-PARTITIONED SCAN: each thread owns 2 vectors (t and t+512) and
// scans ALL 512 codes; no k-groups. Rationale (r13 post-mortem): the
// code-partitioned structure had 32 waves/CU streaming 8 DIFFERENT 2.25KB
// codebook regions -> 18KB live in a ~16KB scalar cache -> chronic misses
// at L2 latency (~255cyc). That thrash is why every load-path fix since r0
// (bytes r4, requests r8, occupancy r9, DS r7, pipelining r11/r13) returned
// ~nothing: L was a miss stream. Here ALL waves stream the SAME 18KB in the
// same order -> K$ holds a sliding window, misses amortize across waves ->
// L ~ hit latency. r13's proven asm ping-pong pipeline (2-code sets,
// wait-BEFORE-issue, sched_barrier fences) rides on top: C~96cyc/step >=
// L_hit -> duty -> ~100%. r1 already proved this partitioning's epilogue
// hazard is global atomics - we keep the r0-proven LDS histogram instead.
// Bonus: per-thread argmin is final -> no cross-wave reduce, no s_mn/s_im
// (16KB LDS freed), epilogue uses all 512 threads.
// Scoring math BIT-IDENTICAL to r0..r13: a = esq[k]; a += zz[c]*e[c],
// c ascending; k ascending with strict-< first-index-wins.
__global__ __launch_bounds__(512, 8) void vq_main(const float* __restrict__ z,
                                                  const float* __restrict__ cb,
                                                  const float* __restrict__ esq,
                                                  float* __restrict__ ws,
                                                  float* __restrict__ zq) {
    __shared__ float s_counts[Kc];         // 2 KB
    __shared__ float s_sums[Kc * Dc];      // 16 KB
    __shared__ float s_loss;

    const int t = threadIdx.x;
    for (int i = t; i < Kc; i += 512) s_counts[i] = 0.f;
    for (int i = t; i < Kc * Dc; i += 512) s_sums[i] = 0.f;
    if (t == 0) s_loss = 0.f;

    const int base = blockIdx.x * 1024;       // 1024-aligned -> one batch idx
    const int b  = base >> 12;                // 4 blocks per image, no wrap
    const int n0 = (base & (HWc - 1)) + t;    // vec0; vec1 = n0 + 512 (<4096)
    const float* zb = z + b * CHWc + n0;

    // zz[c] = (-2*z[vec t][c], -2*z[vec t+512][c]) : lo=vec0, hi=vec1.
    v2f zz[Dc];
#pragma unroll
    for (int c = 0; c < Dc; ++c)
        zz[c] = v2f{-2.0f * zb[c * HWc], -2.0f * zb[c * HWc + 512]};
    // Pin zz VGPR-resident (r9: safe); keeps rematerialized loads out of the
    // volatile-asm pipeline region.
    asm("" : "+v"(zz[0]), "+v"(zz[1]), "+v"(zz[2]), "+v"(zz[3]),
             "+v"(zz[4]), "+v"(zz[5]), "+v"(zz[6]), "+v"(zz[7]));

    float mn0 = 3.4e38f, mn1 = 3.4e38f;
    int   i0 = 0, i1 = 0;

// issue one 2-code set: 2 rows (2x s_load_dwordx8) + esq pair (dwordx2).
// Offsets are wave-uniform SGPR values.
#define SLOAD(R0, R1, EV, ROFF, EOFF)                                  \
    asm volatile("s_load_dwordx8 %0, %3, %5\n\t"                       \
                 "s_load_dwordx8 %1, %3, %6\n\t"                       \
                 "s_load_dwordx2 %2, %4, %7"                           \
                 : "=s"(R0), "=s"(R1), "=s"(EV)                        \
                 : "s"(cb), "s"(esq),                                  \
                   "s"(ROFF), "s"((ROFF) + 32), "s"(EOFF))

// one code, 2 vectors: 8 pk_fma + argmin. op_sel_hi:[1,0,1] broadcasts the
// LOW dword of the sgpr pair (e[2p]); op_sel:[0,1,0] (default op_sel_hi)
// broadcasts the HIGH dword (e[2p+1]). First pk folds the {ev,ev} addend
// (same value & rounding as init-then-fma). Chain: c ascending.
#define CODE1(ROW, EVF, KK)                                            \
    {                                                                  \
        const float ev_ = (EVF);                                       \
        const v2f vev2 = {ev_, ev_};                                   \
        v2f aA;                                                        \
        asm volatile(                                                  \
            "v_pk_fma_f32 %0, %1, %2, %3 op_sel_hi:[1,0,1]\n\t"        \
            "v_pk_fma_f32 %0, %4, %2, %0 op_sel:[0,1,0]"               \
            : "=&v"(aA)                                                \
            : "v"(zz[0]), "s"((ROW).x), "v"(vev2), "v"(zz[1]));        \
        asm volatile(                                                  \
            "v_pk_fma_f32 %0, %1, %2, %0 op_sel_hi:[1,0,1]\n\t"        \
            "v_pk_fma_f32 %0, %3, %2, %0 op_sel:[0,1,0]"               \
            : "+v"(aA) : "v"(zz[2]), "s"((ROW).y), "v"(zz[3]));        \
        asm volatile(                                                  \
            "v_pk_fma_f32 %0, %1, %2, %0 op_sel_hi:[1,0,1]\n\t"        \
            "v_pk_fma_f32 %0, %3, %2, %0 op_sel:[0,1,0]"               \
            : "+v"(aA) : "v"(zz[4]), "s"((ROW).z), "v"(zz[5]));        \
        asm volatile(                                                  \
            "v_pk_fma_f32 %0, %1, %2, %0 op_sel_hi:[1,0,1]\n\t"        \
            "v_pk_fma_f32 %0, %3, %2, %0 op_sel:[0,1,0]"               \
            : "+v"(aA) : "v"(zz[6]), "s"((ROW).w), "v"(zz[7]));        \
        const float a0 = aA.x, a1 = aA.y;                              \
        bool c_;                                                       \
        c_ = a0 < mn0; mn0 = c_ ? a0 : mn0; i0 = c_ ? (KK) : i0;       \
        c_ = a1 < mn1; mn1 = c_ ? a1 : mn1; i1 = c_ ? (KK) : i1;       \
    }

// one pipeline step: wait(current set, aged one compute phase) ->
// issue(next set, clamped at tail) -> compute 2 codes.
#define PIPE_STEP(C0, C1, CEV, N0, N1, NEV, KK)                        \
    asm volatile("s_waitcnt lgkmcnt(0)");                              \
    __builtin_amdgcn_sched_barrier(0);                                 \
    {                                                                  \
        const int ro_ = ro > 16320 ? 16320 : ro;                       \
        const int eo_ = eo > 2040  ? 2040  : eo;                       \
        SLOAD(N0, N1, NEV, ro_, eo_);                                  \
        ro += 64; eo += 8;                                             \
    }                                                                  \
    __builtin_amdgcn_sched_barrier(0);                                 \
    CODE1(C0, (CEV)[0], KK);                                           \
    CODE1(C1, (CEV)[1], (KK) + 1);

    u64x4 A0, A1, B0, B1;
    v2f   Aev, Bev;
    int ro = 0, eo = 0;
    SLOAD(A0, A1, Aev, 0, 0);                 // prologue: set 0 (codes 0,1)
    ro = 64; eo = 8;                          // next to issue: set 1
    int kk = 0;
#pragma unroll 1
    for (int hs = 0; hs < 128; ++hs) {
        PIPE_STEP(A0, A1, Aev, B0, B1, Bev, kk);      // codes kk, kk+1
        PIPE_STEP(B0, B1, Bev, A0, A1, Aev, kk + 2);  // codes kk+2, kk+3
        kk += 4;
    }

#undef PIPE_STEP
#undef CODE1
#undef SLOAD

    __syncthreads();   // zeroed histogram visible to all

    // ---- epilogue: both vectors per thread, all 512 threads active ----
    const float4* cb4 = (const float4*)cb;
    float lsum = 0.f;
    {   // vector 0 (lo halves of zz)
        const float4 qa = cb4[i0 * 2], qb = cb4[i0 * 2 + 1];
        const float q[Dc] = {qa.x, qa.y, qa.z, qa.w, qb.x, qb.y, qb.z, qb.w};
        float* zqv = zq + b * CHWc + n0;
        float zr[Dc];
#pragma unroll
        for (int c = 0; c < Dc; ++c) {
            zr[c] = -0.5f * zz[c].x;          // exact (pow2 scale)
            zqv[c * HWc] = q[c];              // coalesced stores
            const float d = q[c] - zr[c];
            lsum = fmaf(d, d, lsum);
        }
        unsafeAtomicAdd(&s_counts[i0], 1.0f);
#pragma unroll
        for (int c = 0; c < Dc; ++c)
            unsafeAtomicAdd(&s_sums[i0 * Dc + c], zr[c]);
    }
    {   // vector 1 (hi halves of zz)
        const float4 qa = cb4[i1 * 2], qb = cb4[i1 * 2 + 1];
        const float q[Dc] = {qa.x, qa.y, qa.z, qa.w, qb.x, qb.y, qb.z, qb.w};
        float* zqv = zq + b * CHWc + n0 + 512;
        float zr[Dc];
#pragma unroll
        for (int c = 0; c < Dc; ++c) {
            zr[c] = -0.5f * zz[c].y;
            zqv[c * HWc] = q[c];
            const float d = q[c] - zr[c];
            lsum = fmaf(d, d, lsum);
        }
        unsafeAtomicAdd(&s_counts[i1], 1.0f);
#pragma unroll
        for (int c = 0; c < Dc; ++c)
            unsafeAtomicAdd(&s_sums[i1 * Dc + c], zr[c]);
    }
    // loss: wave shuffle reduce, one LDS add per wave
#pragma unroll
    for (int s = 32; s > 0; s >>= 1)
        lsum += __shfl_down(lsum, s);
    if ((t & 63) == 0) unsafeAtomicAdd(&s_loss, lsum);
    __syncthreads();

    // Flush non-zero bins to this block's replica accumulator (all 512 thr).
    float* acc = ws + (blockIdx.x & (REP - 1)) * RSTRIDE;
    for (int i = t; i < Kc; i += 512) {
        const float val = s_counts[i];
        if (val != 0.f) unsafeAtomicAdd(&acc[i], val);
    }
    for (int i = t; i < Kc * Dc; i += 512) {
        const float val = s_sums[i];
        if (val != 0.f) unsafeAtomicAdd(&acc[512 + i], val);
    }
    if (t == 0) unsafeAtomicAdd(&acc[4608], s_loss);
}

// 9 blocks: every block redundantly recomputes the (cheap) counts/cs phase;
// block 0 writes cs + loss, blocks 1..8 each handle 512 of the 4096 K*D
// elements.
__global__ __launch_bounds__(512) void vq_final(const float* __restrict__ ws,
                                                const float* __restrict__ ema_cs,
                                                const float* __restrict__ ema_w,
                                                float* __restrict__ out) {
    constexpr float DEC  = 0.99f;
    constexpr float OMD  = (float)(1.0 - 0.99);      // matches jnp f32 cast
    constexpr float EPSf = 1e-5f;
    constexpr float KEPS = (float)(512 * 1e-5);      // 0.00512
    __shared__ float red[512];
    __shared__ float s_cs[512];

    const int t = threadIdx.x;
    // counts: lane-consecutive reads per replica (coalesced)
    float cnt = 0.f;
#pragma unroll
    for (int r = 0; r < REP; ++r) cnt += ws[r * RSTRIDE + t];
    const float ncs = ema_cs[t] * DEC + cnt * OMD;
    red[t] = ncs;
    __syncthreads();
    for (int s = 256; s > 0; s >>= 1) {
        if (t < s) red[t] += red[t + s];
        __syncthreads();
    }
    const float n  = red[0];
    const float cs = (ncs + EPSf) / (n + KEPS) * n;
    s_cs[t] = cs;

    float* out_loss = out + TOTALc;          // [1]
    float* out_cb   = out + TOTALc + 1;      // [K*D]
    float* out_cs   = out_cb + Kc * Dc;      // [K]
    float* out_nw   = out_cs + Kc;           // [K*D]

    __syncthreads();

    const int blk = blockIdx.x;
    if (blk == 0) {
        out_cs[t] = cs;
        if (t == 0) {
            float ls = 0.f;
#pragma unroll
            for (int r = 0; r < REP; ++r) ls += ws[r * RSTRIDE + 4608];
            out_loss[0] = ls * (1.0f / 2097152.0f);  // /2^21 exact
        }
    } else {
        const int e = (blk - 1) * 512 + t;   // one element per thread
        float sm = 0.f;
#pragma unroll
        for (int r = 0; r < REP; ++r) sm += ws[r * RSTRIDE + 512 + e];
        const float nw = ema_w[e] * DEC + sm * OMD;
        out_nw[e] = nw;
        out_cb[e] = nw / s_cs[e >> 3];
    }
}

extern "C" void kernel_launch(void* const* d_in, const int* in_sizes, int n_in,
                              void* d_out, int out_size, void* d_ws, size_t ws_size,
                              hipStream_t stream) {
    const float* z      = (const float*)d_in[0];
    const float* cb     = (const float*)d_in[1];
    const float* ema_cs = (const float*)d_in[2];
    const float* ema_w  = (const float*)d_in[3];
    float* out = (float*)d_out;
    float* ws  = (float*)d_ws;

    vq_prep<<<32, 256, 0, stream>>>(cb, ws);
    vq_main<<<Mc / 1024, 512, 0, stream>>>(z, cb, ws + ACC_FLOATS, ws, out);
    vq_final<<<9, 512, 0, stream>>>(ws, ema_cs, ema_w, out);
}

// Round 15
// 110.154 us; speedup vs baseline: 1.3051x; 1.3051x over previous
//
#include <hip/hip_runtime.h>

// VQ-VAE forward + EMA update, MI355X.
// Sizes fixed by the reference: B=64, C=D=8, H=W=64, K=512.
constexpr int Kc   = 512;
constexpr int Dc   = 8;
constexpr int HWc  = 4096;            // 64*64
constexpr int CHWc = Dc * HWc;        // 32768
constexpr int Mc   = 64 * HWc;        // 262144 vectors
constexpr int TOTALc = Mc * Dc;       // 2097152 elements of z / z_q

// 8 replica accumulators (one per XCD via blockIdx&7) to cut atomic contention.
constexpr int REP      = 8;
constexpr int RSTRIDE  = 4616;        // 512 counts + 4096 sums + 1 loss + 7 pad
constexpr int ACC_FLOATS = REP * RSTRIDE;   // 36928 floats (~148 KB)
// d_ws float layout:
//   [0 .. ACC_FLOATS)            replica accumulators (counts | sums | loss | pad) x8
//   [ACC_FLOATS .. +512)         e_sq[k]

typedef float v2f  __attribute__((ext_vector_type(2)));
typedef unsigned long long ull;
typedef ull  u64x4 __attribute__((ext_vector_type(4)));

__global__ __launch_bounds__(256) void vq_prep(const float* __restrict__ cb,
                                               float* __restrict__ ws) {
    const int tid = blockIdx.x * 256 + threadIdx.x;
    float4* w4 = (float4*)ws;
    for (int i = tid; i < ACC_FLOATS / 4; i += gridDim.x * 256)
        w4[i] = float4{0.f, 0.f, 0.f, 0.f};
    if (blockIdx.x == 0) {
        for (int k = threadIdx.x; k < Kc; k += 256) {
            float s = 0.f;
#pragma unroll
            for (int c = 0; c < Dc; ++c) {
                const float e = cb[k * Dc + c];
                s = fmaf(e, e, s);
            }
            ws[ACC_FLOATS + k] = s;
        }
    }
}

// 512 blocks x 512 threads; block owns 512 consecutive vectors.
// 8 k-groups x 1 wave; lane l scores V=8 vectors (l+64j, j=0..7) as 4 v2f
// pairs via v_pk_fma_f32 (codebook pair in SGPR pair, lo/hi via op_sel).
// WHY V=8 (r14 post-mortem): unified duty model duty=C/(C+max(0,L-age)).
// r14 proved L~255-270cyc is the INTRINSIC scalar-load latency (same-address
// streams didn't help -> not thrash), and VALU-busy is pinned at 27-28us =
// ~88% of this algorithm's VALU floor -> duty is the only lever. The r13
// 1-deep wait-before-issue pipeline ages loads by exactly C; r13's C~176 ->
// duty 63% (measured 62-64). Here C per 2-code step ~ 2x(32pk x4cyc +
// 24 argmin-cyc) ~ 350 > L -> residual stall ~0 -> duty ~95%+.
// Resources: VGPR~110 (zz=64) capped 128 by __launch_bounds__(512,4);
// 2 blocks/CU exactly (grid 512); LDS 51.2KB; SGPR payload 36 (r13-proven).
// Scoring math BIT-IDENTICAL to r0..r13: a = esq[k]; a += zz[c]*e[c],
// c ascending; strict-< first-index-wins; k-groups ascending.
__global__ __launch_bounds__(512, 4) void vq_main(const float* __restrict__ z,
                                                  const float* __restrict__ cb,
                                                  const float* __restrict__ esq,
                                                  float* __restrict__ ws,
                                                  float* __restrict__ zq) {
    __shared__ float s_mn[8][512];         // 16 KB
    __shared__ int   s_im[8][512];         // 16 KB
    __shared__ float s_counts[Kc];         // 2 KB
    __shared__ float s_sums[Kc * Dc];      // 16 KB
    __shared__ float s_loss;

    const int t = threadIdx.x;
    for (int i = t; i < Kc; i += 512) s_counts[i] = 0.f;
    for (int i = t; i < Kc * Dc; i += 512) s_sums[i] = 0.f;
    if (t == 0) s_loss = 0.f;

    const int l = t & 63;
    // wave-uniform k-group; readfirstlane keeps codebook addresses provably
    // uniform -> SGPR pointers for the asm s_loads.
    const int g  = __builtin_amdgcn_readfirstlane(t >> 6);   // 0..7
    const int k0 = g << 6;

    const int base = blockIdx.x * 512;        // 512-aligned -> one batch idx
    const int b  = base >> 12;                // 8 blocks per image
    const int n0 = (base & (HWc - 1)) + l;    // +64*j (j<8) never wraps 4096
    const float* zb = z + b * CHWc + n0;

    // zzP[c] = (-2*z[vec l+128P][c], -2*z[vec l+128P+64][c]) : 4 pairs = 8 vec.
    v2f zz0[Dc], zz1[Dc], zz2[Dc], zz3[Dc];
#pragma unroll
    for (int c = 0; c < Dc; ++c) {
        zz0[c] = v2f{-2.0f * zb[c * HWc],       -2.0f * zb[c * HWc +  64]};
        zz1[c] = v2f{-2.0f * zb[c * HWc + 128], -2.0f * zb[c * HWc + 192]};
        zz2[c] = v2f{-2.0f * zb[c * HWc + 256], -2.0f * zb[c * HWc + 320]};
        zz3[c] = v2f{-2.0f * zb[c * HWc + 384], -2.0f * zb[c * HWc + 448]};
    }
    // Pin zz VGPR-resident (keeps rematerialized loads out of the pipeline).
    asm("" : "+v"(zz0[0]), "+v"(zz0[1]), "+v"(zz0[2]), "+v"(zz0[3]),
             "+v"(zz0[4]), "+v"(zz0[5]), "+v"(zz0[6]), "+v"(zz0[7]));
    asm("" : "+v"(zz1[0]), "+v"(zz1[1]), "+v"(zz1[2]), "+v"(zz1[3]),
             "+v"(zz1[4]), "+v"(zz1[5]), "+v"(zz1[6]), "+v"(zz1[7]));
    asm("" : "+v"(zz2[0]), "+v"(zz2[1]), "+v"(zz2[2]), "+v"(zz2[3]),
             "+v"(zz2[4]), "+v"(zz2[5]), "+v"(zz2[6]), "+v"(zz2[7]));
    asm("" : "+v"(zz3[0]), "+v"(zz3[1]), "+v"(zz3[2]), "+v"(zz3[3]),
             "+v"(zz3[4]), "+v"(zz3[5]), "+v"(zz3[6]), "+v"(zz3[7]));

    const float* cbg = cb + (k0 << 3);        // this group's 64 rows (2 KB)
    const float* eqg = esq + k0;

    float mn0 = 3.4e38f, mn1 = 3.4e38f, mn2 = 3.4e38f, mn3 = 3.4e38f;
    float mn4 = 3.4e38f, mn5 = 3.4e38f, mn6 = 3.4e38f, mn7 = 3.4e38f;
    int   i0 = k0, i1 = k0, i2 = k0, i3 = k0;
    int   i4 = k0, i5 = k0, i6 = k0, i7 = k0;

// issue one 2-code set: 2 rows (2x s_load_dwordx8) + esq pair (dwordx2).
#define SLOAD(R0, R1, EV, ROFF, EOFF)                                  \
    asm volatile("s_load_dwordx8 %0, %3, %5\n\t"                       \
                 "s_load_dwordx8 %1, %3, %6\n\t"                       \
                 "s_load_dwordx2 %2, %4, %7"                           \
                 : "=s"(R0), "=s"(R1), "=s"(EV)                        \
                 : "s"(cbg), "s"(eqg),                                 \
                   "s"(ROFF), "s"((ROFF) + 32), "s"(EOFF))

// 8 pk_fma covering c-pair (C0,C1) for all 4 vector-pairs.
#define PK8(Q, C0, C1)                                                 \
    asm volatile(                                                      \
        "v_pk_fma_f32 %0, %4, %12, %0 op_sel_hi:[1,0,1]\n\t"           \
        "v_pk_fma_f32 %1, %5, %12, %1 op_sel_hi:[1,0,1]\n\t"           \
        "v_pk_fma_f32 %2, %6, %12, %2 op_sel_hi:[1,0,1]\n\t"           \
        "v_pk_fma_f32 %3, %7, %12, %3 op_sel_hi:[1,0,1]\n\t"           \
        "v_pk_fma_f32 %0, %8, %12, %0 op_sel:[0,1,0]\n\t"              \
        "v_pk_fma_f32 %1, %9, %12, %1 op_sel:[0,1,0]\n\t"              \
        "v_pk_fma_f32 %2, %10, %12, %2 op_sel:[0,1,0]\n\t"             \
        "v_pk_fma_f32 %3, %11, %12, %3 op_sel:[0,1,0]"                 \
        : "+v"(aA), "+v"(aB), "+v"(aC), "+v"(aD)                       \
        : "v"(zz0[C0]), "v"(zz1[C0]), "v"(zz2[C0]), "v"(zz3[C0]),      \
          "v"(zz0[C1]), "v"(zz1[C1]), "v"(zz2[C1]), "v"(zz3[C1]),      \
          "s"(Q))

// one code, 8 vectors: 32 pk_fma + argmin. op_sel_hi:[1,0,1] = lo dword of
// the sgpr pair (e[2p]); op_sel:[0,1,0] = hi dword (e[2p+1]). First block
// folds the {ev,ev} addend (same value & rounding as init-then-fma).
#define CODE1(ROW, EVF, KK)                                            \
    {                                                                  \
        const float ev_ = (EVF);                                       \
        const v2f vev2 = {ev_, ev_};                                   \
        v2f aA, aB, aC, aD;                                            \
        asm volatile(                                                  \
            "v_pk_fma_f32 %0, %4, %8, %9 op_sel_hi:[1,0,1]\n\t"        \
            "v_pk_fma_f32 %1, %5, %8, %9 op_sel_hi:[1,0,1]\n\t"        \
            "v_pk_fma_f32 %2, %6, %8, %9 op_sel_hi:[1,0,1]\n\t"        \
            "v_pk_fma_f32 %3, %7, %8, %9 op_sel_hi:[1,0,1]\n\t"        \
            "v_pk_fma_f32 %0, %10, %8, %0 op_sel:[0,1,0]\n\t"          \
            "v_pk_fma_f32 %1, %11, %8, %1 op_sel:[0,1,0]\n\t"          \
            "v_pk_fma_f32 %2, %12, %8, %2 op_sel:[0,1,0]\n\t"          \
            "v_pk_fma_f32 %3, %13, %8, %3 op_sel:[0,1,0]"              \
            : "=&v"(aA), "=&v"(aB), "=&v"(aC), "=&v"(aD)               \
            : "v"(zz0[0]), "v"(zz1[0]), "v"(zz2[0]), "v"(zz3[0]),      \
              "s"((ROW).x), "v"(vev2),                                 \
              "v"(zz0[1]), "v"(zz1[1]), "v"(zz2[1]), "v"(zz3[1]));     \
        PK8((ROW).y, 2, 3);                                            \
        PK8((ROW).z, 4, 5);                                            \
        PK8((ROW).w, 6, 7);                                            \
        bool c_;                                                       \
        c_ = aA.x < mn0; i0 = c_ ? (KK) : i0; mn0 = c_ ? aA.x : mn0;   \
        c_ = aA.y < mn1; i1 = c_ ? (KK) : i1; mn1 = c_ ? aA.y : mn1;   \
        c_ = aB.x < mn2; i2 = c_ ? (KK) : i2; mn2 = c_ ? aB.x : mn2;   \
        c_ = aB.y < mn3; i3 = c_ ? (KK) : i3; mn3 = c_ ? aB.y : mn3;   \
        c_ = aC.x < mn4; i4 = c_ ? (KK) : i4; mn4 = c_ ? aC.x : mn4;   \
        c_ = aC.y < mn5; i5 = c_ ? (KK) : i5; mn5 = c_ ? aC.y : mn5;   \
        c_ = aD.x < mn6; i6 = c_ ? (KK) : i6; mn6 = c_ ? aD.x : mn6;   \
        c_ = aD.y < mn7; i7 = c_ ? (KK) : i7; mn7 = c_ ? aD.y : mn7;   \
    }

// one pipeline step: wait(current set, aged one ~350cyc compute phase) ->
// issue(next set, clamped at tail) -> compute 2 codes.
#define PIPE_STEP(C0, C1, CEV, N0, N1, NEV, KK)                        \
    asm volatile("s_waitcnt lgkmcnt(0)");                              \
    __builtin_amdgcn_sched_barrier(0);                                 \
    {                                                                  \
        const int ro_ = ro > 1984 ? 1984 : ro;                         \
        const int eo_ = eo > 248  ? 248  : eo;                         \
        SLOAD(N0, N1, NEV, ro_, eo_);                                  \
        ro += 64; eo += 8;                                             \
    }                                                                  \
    __builtin_amdgcn_sched_barrier(0);                                 \
    CODE1(C0, (CEV)[0], KK);                                           \
    CODE1(C1, (CEV)[1], (KK) + 1);

    u64x4 A0, A1, B0, B1;
    v2f   Aev, Bev;
    int ro = 0, eo = 0;
    SLOAD(A0, A1, Aev, 0, 0);                 // prologue: set 0 (codes 0,1)
    ro = 64; eo = 8;                          // next to issue: set 1
    int kk = k0;
#pragma unroll 1
    for (int hs = 0; hs < 16; ++hs) {
        PIPE_STEP(A0, A1, Aev, B0, B1, Bev, kk);      // codes kk, kk+1
        PIPE_STEP(B0, B1, Bev, A0, A1, Aev, kk + 2);  // codes kk+2, kk+3
        kk += 4;
    }

#undef PIPE_STEP
#undef CODE1
#undef PK8
#undef SLOAD

    s_mn[g][l]       = mn0;  s_im[g][l]       = i0;
    s_mn[g][l +  64] = mn1;  s_im[g][l +  64] = i1;
    s_mn[g][l + 128] = mn2;  s_im[g][l + 128] = i2;
    s_mn[g][l + 192] = mn3;  s_im[g][l + 192] = i3;
    s_mn[g][l + 256] = mn4;  s_im[g][l + 256] = i4;
    s_mn[g][l + 320] = mn5;  s_im[g][l + 320] = i5;
    s_mn[g][l + 384] = mn6;  s_im[g][l + 384] = i6;
    s_mn[g][l + 448] = mn7;  s_im[g][l + 448] = i7;
    __syncthreads();

    // ---- epilogue: one vector per thread, all 512 threads active ----
    {
        const int v = t;                      // block-local vector id
        float mn = s_mn[0][v];
        int   im = s_im[0][v];
#pragma unroll
        for (int gg = 1; gg < 8; ++gg) {
            const float m2 = s_mn[gg][v];     // groups ascending in k:
            const int   j2 = s_im[gg][v];     // strict < keeps first index
            const bool  c2 = m2 < mn;
            mn = c2 ? m2 : mn;
            im = c2 ? j2 : im;
        }

        // Gather old-codebook row (16 KB table, L1-hot; 32B/lane).
        const float4* cb4 = (const float4*)cb;
        const float4 qa = cb4[im * 2], qb = cb4[im * 2 + 1];
        const float q[Dc] = {qa.x, qa.y, qa.z, qa.w, qb.x, qb.y, qb.z, qb.w};

        const int nv = (base & (HWc - 1)) + v;
        const float* zv = z + b * CHWc + nv;  // re-read z (L1/L2-hot)
        float* zqv = zq + b * CHWc + nv;
        float lsum = 0.f;
        float zr[Dc];
#pragma unroll
        for (int c = 0; c < Dc; ++c) {
            zr[c] = zv[c * HWc];
            zqv[c * HWc] = q[c];              // coalesced stores
            const float d = q[c] - zr[c];
            lsum = fmaf(d, d, lsum);
        }

        // Per-block LDS histogram (ds_add_f32) — coalesces same-index hits.
        unsafeAtomicAdd(&s_counts[im], 1.0f);
#pragma unroll
        for (int c = 0; c < Dc; ++c)
            unsafeAtomicAdd(&s_sums[im * Dc + c], zr[c]);

        // loss: wave shuffle reduce, one LDS add per wave
#pragma unroll
        for (int s = 32; s > 0; s >>= 1)
            lsum += __shfl_down(lsum, s);
        if ((t & 63) == 0) unsafeAtomicAdd(&s_loss, lsum);
    }
    __syncthreads();

    // Flush non-zero bins to this block's replica accumulator (all 512 thr).
    float* acc = ws + (blockIdx.x & (REP - 1)) * RSTRIDE;
    for (int i = t; i < Kc; i += 512) {
        const float val = s_counts[i];
        if (val != 0.f) unsafeAtomicAdd(&acc[i], val);
    }
    for (int i = t; i < Kc * Dc; i += 512) {
        const float val = s_sums[i];
        if (val != 0.f) unsafeAtomicAdd(&acc[512 + i], val);
    }
    if (t == 0) unsafeAtomicAdd(&acc[4608], s_loss);
}

// 9 blocks: every block redundantly recomputes the (cheap) counts/cs phase;
// block 0 writes cs + loss, blocks 1..8 each handle 512 of the 4096 K*D
// elements.
__global__ __launch_bounds__(512) void vq_final(const float* __restrict__ ws,
                                                const float* __restrict__ ema_cs,
                                                const float* __restrict__ ema_w,
                                                float* __restrict__ out) {
    constexpr float DEC  = 0.99f;
    constexpr float OMD  = (float)(1.0 - 0.99);      // matches jnp f32 cast
    constexpr float EPSf = 1e-5f;
    constexpr float KEPS = (float)(512 * 1e-5);      // 0.00512
    __shared__ float red[512];
    __shared__ float s_cs[512];

    const int t = threadIdx.x;
    // counts: lane-consecutive reads per replica (coalesced)
    float cnt = 0.f;
#pragma unroll
    for (int r = 0; r < REP; ++r) cnt += ws[r * RSTRIDE + t];
    const float ncs = ema_cs[t] * DEC + cnt * OMD;
    red[t] = ncs;
    __syncthreads();
    for (int s = 256; s > 0; s >>= 1) {
        if (t < s) red[t] += red[t + s];
        __syncthreads();
    }
    const float n  = red[0];
    const float cs = (ncs + EPSf) / (n + KEPS) * n;
    s_cs[t] = cs;

    float* out_loss = out + TOTALc;          // [1]
    float* out_cb   = out + TOTALc + 1;      // [K*D]
    float* out_cs   = out_cb + Kc * Dc;      // [K]
    float* out_nw   = out_cs + Kc;           // [K*D]

    __syncthreads();

    const int blk = blockIdx.x;
    if (blk == 0) {
        out_cs[t] = cs;
        if (t == 0) {
            float ls = 0.f;
#pragma unroll
            for (int r = 0; r < REP; ++r) ls += ws[r * RSTRIDE + 4608];
            out_loss[0] = ls * (1.0f / 2097152.0f);  // /2^21 exact
        }
    } else {
        const int e = (blk - 1) * 512 + t;   // one element per thread
        float sm = 0.f;
#pragma unroll
        for (int r = 0; r < REP; ++r) sm += ws[r * RSTRIDE + 512 + e];
        const float nw = ema_w[e] * DEC + sm * OMD;
        out_nw[e] = nw;
        out_cb[e] = nw / s_cs[e >> 3];
    }
}

extern "C" void kernel_launch(void* const* d_in, const int* in_sizes, int n_in,
                              void* d_out, int out_size, void* d_ws, size_t ws_size,
                              hipStream_t stream) {
    const float* z      = (const float*)d_in[0];
    const float* cb     = (const float*)d_in[1];
    const float* ema_cs = (const float*)d_in[2];
    const float* ema_w  = (const float*)d_in[3];
    float* out = (float*)d_out;
    float* ws  = (float*)d_ws;

    vq_prep<<<32, 256, 0, stream>>>(cb, ws);
    vq_main<<<Mc / 512, 512, 0, stream>>>(z, cb, ws + ACC_FLOATS, ws, out);
    vq_final<<<9, 512, 0, stream>>>(ws, ema_cs, ema_w, out);
}

// Round 16
// 108.189 us; speedup vs baseline: 1.3289x; 1.0182x over previous
//
#include <hip/hip_runtime.h>

// VQ-VAE forward + EMA update, MI355X.
// Sizes fixed by the reference: B=64, C=D=8, H=W=64, K=512.
constexpr int Kc   = 512;
constexpr int Dc   = 8;
constexpr int HWc  = 4096;            // 64*64
constexpr int CHWc = Dc * HWc;        // 32768
constexpr int Mc   = 64 * HWc;        // 262144 vectors
constexpr int TOTALc = Mc * Dc;       // 2097152 elements of z / z_q

// 8 replica accumulators (one per XCD via blockIdx&7) to cut atomic contention.
constexpr int REP      = 8;
constexpr int RSTRIDE  = 4616;        // 512 counts + 4096 sums + 1 loss + 7 pad
constexpr int ACC_FLOATS = REP * RSTRIDE;   // 36928 floats (~148 KB)
// d_ws float layout:
//   [0 .. ACC_FLOATS)            replica accumulators (counts | sums | loss | pad) x8
//   [ACC_FLOATS .. +512)         e_sq[k]

typedef float v2f __attribute__((ext_vector_type(2)));
typedef float f4  __attribute__((ext_vector_type(4)));
typedef unsigned long long ull;
typedef ull  u64x4 __attribute__((ext_vector_type(4)));

__global__ __launch_bounds__(256) void vq_prep(const float* __restrict__ cb,
                                               float* __restrict__ ws) {
    const int tid = blockIdx.x * 256 + threadIdx.x;
    float4* w4 = (float4*)ws;
    for (int i = tid; i < ACC_FLOATS / 4; i += gridDim.x * 256)
        w4[i] = float4{0.f, 0.f, 0.f, 0.f};
    if (blockIdx.x == 0) {
        for (int k = threadIdx.x; k < Kc; k += 256) {
            float s = 0.f;
#pragma unroll
            for (int c = 0; c < Dc; ++c) {
                const float e = cb[k * Dc + c];
                s = fmaf(e, e, s);
            }
            ws[ACC_FLOATS + k] = s;
        }
    }
}

// 1024 blocks x 512 threads; block owns 256 consecutive vectors.
// 8 k-groups x 1 wave; lane l scores V=4 vectors (l,l+64,l+128,l+192) via
// v_pk_fma_f32 (codebook pair in SGPR pair, lo/hi broadcast via op_sel),
// with a one-deep SGPR ping-pong prefetch of next iteration's rows+esq.
// BEST-MEASURED VARIANT (r11: vq_main 45.1-45.8us, total 107.06us,
// VALUBusy 62%, absmax bit-exact). Session ledger (16 rounds): VALU-busy is
// invariant at 26-28us = ~88% of the algorithm's issue floor; per-wave duty
// is pinned at 49-64% across every structure tried (SMEM bytes/requests/
// pipelining at HIP and asm level, DS, vector path, occupancy 2-8 waves,
// V=2/4/8, shared vs split code streams) -> the residual stall is intrinsic
// scalar-load service latency (~255cyc) that multi-wave TLP does not hide
// on this chip; not movable at source level.
// Math BIT-IDENTICAL to the original baseline: a = esq[k]; a += zz[c]*e[c],
// c ascending; strict-< first-index-wins; groups ascending in k.
__global__ __launch_bounds__(512, 8) void vq_main(const float* __restrict__ z,
                                                  const float* __restrict__ cb,
                                                  const float* __restrict__ esq,
                                                  float* __restrict__ ws,
                                                  float* __restrict__ zq) {
    __shared__ float s_mn[8][256];         // 8 KB
    __shared__ int   s_im[8][256];         // 8 KB
    __shared__ float s_counts[Kc];         // 2 KB
    __shared__ float s_sums[Kc * Dc];      // 16 KB
    __shared__ float s_loss;

    const int t = threadIdx.x;
    for (int i = t; i < Kc; i += 512) s_counts[i] = 0.f;
    for (int i = t; i < Kc * Dc; i += 512) s_sums[i] = 0.f;
    if (t == 0) s_loss = 0.f;

    const int l = t & 63;
    // wave-uniform k-group; readfirstlane keeps codebook indices provably
    // uniform -> s_load (scalar) path for cb/esq.
    const int g  = __builtin_amdgcn_readfirstlane(t >> 6);   // 0..7
    const int k0 = g << 6;

    const int base = blockIdx.x * 256;        // 256-aligned -> one batch idx
    const int b  = base >> 12;
    const int n0 = (base & (HWc - 1)) + l;    // +64*j below never wraps 4096
    const float* zb = z + b * CHWc + n0;

    // zzA[c] = (-2*z[vec l][c], -2*z[vec l+64][c]); zzB: vecs l+128, l+192.
    v2f zzA[Dc], zzB[Dc];
#pragma unroll
    for (int c = 0; c < Dc; ++c) {
        zzA[c] = v2f{-2.0f * zb[c * HWc],       -2.0f * zb[c * HWc + 64]};
        zzB[c] = v2f{-2.0f * zb[c * HWc + 128], -2.0f * zb[c * HWc + 192]};
    }

    const float* cbg = cb + (k0 << 3);        // uniform: this group's 64 rows
    const float* eqg = esq + k0;

    // ---- prologue: load iteration 0's rows + esq into SGPRs ----
    u64x4 nr0 = *(const u64x4*)(cbg + 0);     // s_load_dwordx8 (row 4*0+0)
    u64x4 nr1 = *(const u64x4*)(cbg + 8);
    u64x4 nr2 = *(const u64x4*)(cbg + 16);
    u64x4 nr3 = *(const u64x4*)(cbg + 24);
    f4    nev = *(const f4*)(eqg);            // s_load_dwordx4

    float mn0 = 3.4e38f, mn1 = 3.4e38f, mn2 = 3.4e38f, mn3 = 3.4e38f;
    int   i0 = k0, i1 = k0, i2 = k0, i3 = k0;
#pragma unroll 2
    for (int kq = 0; kq < 16; ++kq) {
        // consume the prefetched set
        const u64x4 r0 = nr0, r1 = nr1, r2 = nr2, r3 = nr3;
        const f4 ev4 = nev;

        // issue NEXT iteration's loads before the compute phase
        const int kqn = (kq + 1 < 16) ? kq + 1 : 15;   // clamped, branchless
        nr0 = *(const u64x4*)(cbg + 32 * kqn + 0);
        nr1 = *(const u64x4*)(cbg + 32 * kqn + 8);
        nr2 = *(const u64x4*)(cbg + 32 * kqn + 16);
        nr3 = *(const u64x4*)(cbg + 32 * kqn + 24);
        nev = *(const f4*)(eqg + 4 * kqn);

        const int kb = k0 + kq * 4;
#pragma unroll
        for (int j = 0; j < 4; ++j) {
            const int k = kb + j;
            const u64x4 row = (j == 0) ? r0 : (j == 1) ? r1 : (j == 2) ? r2 : r3;
            const ull q0 = row.x, q1 = row.y, q2 = row.z, q3 = row.w;
            const float ev = ev4[j];
            const v2f vev2 = {ev, ev};
            v2f aA, aB;
            // op_sel_hi:[1,0,1] broadcasts the LOW dword of the sgpr pair
            // (e[2p]); op_sel:[0,1,0] (default op_sel_hi) broadcasts the
            // HIGH dword (e[2p+1]). First step folds the {ev,ev} addend
            // directly (same value & rounding as init-then-fma).
            asm("v_pk_fma_f32 %0, %2, %4, %5 op_sel_hi:[1,0,1]\n\t"
                "v_pk_fma_f32 %1, %3, %4, %5 op_sel_hi:[1,0,1]\n\t"
                "v_pk_fma_f32 %0, %6, %4, %0 op_sel:[0,1,0]\n\t"
                "v_pk_fma_f32 %1, %7, %4, %1 op_sel:[0,1,0]"
                : "=&v"(aA), "=&v"(aB)
                : "v"(zzA[0]), "v"(zzB[0]), "s"(q0), "v"(vev2),
                  "v"(zzA[1]), "v"(zzB[1]));
#define PKSTEP(Q, P0, P1)                                              \
            asm("v_pk_fma_f32 %0, %2, %4, %0 op_sel_hi:[1,0,1]\n\t"    \
                "v_pk_fma_f32 %1, %3, %4, %1 op_sel_hi:[1,0,1]\n\t"    \
                "v_pk_fma_f32 %0, %5, %4, %0 op_sel:[0,1,0]\n\t"       \
                "v_pk_fma_f32 %1, %6, %4, %1 op_sel:[0,1,0]"           \
                : "+v"(aA), "+v"(aB)                                   \
                : "v"(zzA[P0]), "v"(zzB[P0]), "s"(Q), "v"(zzA[P1]), "v"(zzB[P1]))
            PKSTEP(q1, 2, 3);
            PKSTEP(q2, 4, 5);
            PKSTEP(q3, 6, 7);
#undef PKSTEP
            const float a0 = aA.x, a1 = aA.y, a2 = aB.x, a3 = aB.y;
            bool c;
            c = a0 < mn0; mn0 = c ? a0 : mn0; i0 = c ? k : i0;
            c = a1 < mn1; mn1 = c ? a1 : mn1; i1 = c ? k : i1;
            c = a2 < mn2; mn2 = c ? a2 : mn2; i2 = c ? k : i2;
            c = a3 < mn3; mn3 = c ? a3 : mn3; i3 = c ? k : i3;
        }
    }
    s_mn[g][l]       = mn0;  s_im[g][l]       = i0;
    s_mn[g][l +  64] = mn1;  s_im[g][l +  64] = i1;
    s_mn[g][l + 128] = mn2;  s_im[g][l + 128] = i2;
    s_mn[g][l + 192] = mn3;  s_im[g][l + 192] = i3;
    __syncthreads();

    if (t < 256) {
        const int v = t;                      // block-local vector id
        float mn = s_mn[0][v];
        int   im = s_im[0][v];
#pragma unroll
        for (int gg = 1; gg < 8; ++gg) {
            const float m2 = s_mn[gg][v];     // groups ascending in k:
            const int   j2 = s_im[gg][v];     // strict < keeps first index
            const bool  c2 = m2 < mn;
            mn = c2 ? m2 : mn;
            im = c2 ? j2 : im;
        }

        // Gather old-codebook row (16 KB table, L1-hot; 32B/lane).
        const float4* cb4 = (const float4*)cb;
        const float4 qa = cb4[im * 2], qb = cb4[im * 2 + 1];
        const float q[Dc] = {qa.x, qa.y, qa.z, qa.w, qb.x, qb.y, qb.z, qb.w};

        const int nv = (base & (HWc - 1)) + v;
        const float* zv = z + b * CHWc + nv;  // re-read z (L1/L2-hot)
        float* zqv = zq + b * CHWc + nv;
        float lsum = 0.f;
        float zr[Dc];
#pragma unroll
        for (int c = 0; c < Dc; ++c) {
            zr[c] = zv[c * HWc];
            zqv[c * HWc] = q[c];              // coalesced stores
            const float d = q[c] - zr[c];
            lsum = fmaf(d, d, lsum);
        }

        // Per-block LDS histogram (ds_add_f32) — coalesces same-index hits.
        unsafeAtomicAdd(&s_counts[im], 1.0f);
#pragma unroll
        for (int c = 0; c < Dc; ++c)
            unsafeAtomicAdd(&s_sums[im * Dc + c], zr[c]);
        unsafeAtomicAdd(&s_loss, lsum);
    }
    __syncthreads();

    // Flush non-zero bins to this block's replica accumulator (all 512 thr).
    float* acc = ws + (blockIdx.x & (REP - 1)) * RSTRIDE;
    for (int i = t; i < Kc; i += 512) {
        const float val = s_counts[i];
        if (val != 0.f) unsafeAtomicAdd(&acc[i], val);
    }
    for (int i = t; i < Kc * Dc; i += 512) {
        const float val = s_sums[i];
        if (val != 0.f) unsafeAtomicAdd(&acc[512 + i], val);
    }
    if (t == 0) unsafeAtomicAdd(&acc[4608], s_loss);
}

// 9 blocks: every block redundantly recomputes the (cheap) counts/cs phase;
// block 0 writes cs + loss, blocks 1..8 each handle 512 of the 4096 K*D
// elements.
__global__ __launch_bounds__(512) void vq_final(const float* __restrict__ ws,
                                                const float* __restrict__ ema_cs,
                                                const float* __restrict__ ema_w,
                                                float* __restrict__ out) {
    constexpr float DEC  = 0.99f;
    constexpr float OMD  = (float)(1.0 - 0.99);      // matches jnp f32 cast
    constexpr float EPSf = 1e-5f;
    constexpr float KEPS = (float)(512 * 1e-5);      // 0.00512
    __shared__ float red[512];
    __shared__ float s_cs[512];

    const int t = threadIdx.x;
    // counts: lane-consecutive reads per replica (coalesced)
    float cnt = 0.f;
#pragma unroll
    for (int r = 0; r < REP; ++r) cnt += ws[r * RSTRIDE + t];
    const float ncs = ema_cs[t] * DEC + cnt * OMD;
    red[t] = ncs;
    __syncthreads();
    for (int s = 256; s > 0; s >>= 1) {
        if (t < s) red[t] += red[t + s];
        __syncthreads();
    }
    const float n  = red[0];
    const float cs = (ncs + EPSf) / (n + KEPS) * n;
    s_cs[t] = cs;

    float* out_loss = out + TOTALc;          // [1]
    float* out_cb   = out + TOTALc + 1;      // [K*D]
    float* out_cs   = out_cb + Kc * Dc;      // [K]
    float* out_nw   = out_cs + Kc;           // [K*D]

    __syncthreads();

    const int blk = blockIdx.x;
    if (blk == 0) {
        out_cs[t] = cs;
        if (t == 0) {
            float ls = 0.f;
#pragma unroll
            for (int r = 0; r < REP; ++r) ls += ws[r * RSTRIDE + 4608];
            out_loss[0] = ls * (1.0f / 2097152.0f);  // /2^21 exact
        }
    } else {
        const int e = (blk - 1) * 512 + t;   // one element per thread
        float sm = 0.f;
#pragma unroll
        for (int r = 0; r < REP; ++r) sm += ws[r * RSTRIDE + 512 + e];
        const float nw = ema_w[e] * DEC + sm * OMD;
        out_nw[e] = nw;
        out_cb[e] = nw / s_cs[e >> 3];
    }
}

extern "C" void kernel_launch(void* const* d_in, const int* in_sizes, int n_in,
                              void* d_out, int out_size, void* d_ws, size_t ws_size,
                              hipStream_t stream) {
    const float* z      = (const float*)d_in[0];
    const float* cb     = (const float*)d_in[1];
    const float* ema_cs = (const float*)d_in[2];
    const float* ema_w  = (const float*)d_in[3];
    float* out = (float*)d_out;
    float* ws  = (float*)d_ws;

    vq_prep<<<32, 256, 0, stream>>>(cb, ws);
    vq_main<<<Mc / 256, 512, 0, stream>>>(z, cb, ws + ACC_FLOATS, ws, out);
    vq_final<<<9, 512, 0, stream>>>(ws, ema_cs, ema_w, out);
}